// Round 1
// baseline (1069.111 us; speedup 1.0000x reference)
//
#include <hip/hip_runtime.h>

// ---------------- types ----------------
typedef __attribute__((ext_vector_type(8))) short short8;   // 8 bf16 in 4 VGPRs
typedef __attribute__((ext_vector_type(4))) float floatx4;

static __device__ __forceinline__ unsigned short f2bf(float f) {
    unsigned int u = __float_as_uint(f);
    unsigned int r = (u + 0x7FFFu + ((u >> 16) & 1u)) >> 16;   // RNE
    return (unsigned short)r;
}

// ---------------- constants ----------------
#define BATCH 4
#define NPTS 100000
#define CIN 128
#define COUT 64
#define HH 256
#define WW 256
#define HP 258          // padded
#define WP 258

// ws layout (bytes)
#define OFF_BUF1 0
#define SZ_BUF   (BATCH * HP * WP * COUT * 2)          // 34,080,768
#define OFF_BUF2 (OFF_BUF1 + SZ_BUF)
#define OFF_WB1  (OFF_BUF2 + SZ_BUF)                    // 68,161,536
#define SZ_WB    (9 * COUT * COUT * 2)                  // 73,728
#define OFF_WB2  (OFF_WB1 + SZ_WB)
#define OFF_BIAS1 (OFF_WB2 + SZ_WB)                     // 68,308,992
#define OFF_BIAS2 (OFF_BIAS1 + 256)

// ---------------- prep: fold BN into conv weights, transpose to [tap][co][ci] bf16 ----------------
__global__ void prep_weights(const float* __restrict__ cw1, const float* __restrict__ cb1,
                             const float* __restrict__ g1, const float* __restrict__ bb1,
                             const float* __restrict__ m1, const float* __restrict__ v1,
                             const float* __restrict__ cw2, const float* __restrict__ cb2,
                             const float* __restrict__ g2, const float* __restrict__ bb2,
                             const float* __restrict__ m2, const float* __restrict__ v2,
                             unsigned short* __restrict__ Wb1, unsigned short* __restrict__ Wb2,
                             float* __restrict__ bias1, float* __restrict__ bias2) {
    int idx = blockIdx.x * 256 + threadIdx.x;           // 0 .. 73727
    int l = idx / 36864;
    int r = idx - l * 36864;
    int ci = r & 63;
    int co = (r >> 6) & 63;
    int tap = r >> 12;
    const float* w  = l ? cw2 : cw1;
    const float* g  = l ? g2  : g1;
    const float* v  = l ? v2  : v1;
    float s = g[co] * rsqrtf(v[co] + 1e-5f);
    float wv = w[(co * 64 + ci) * 9 + tap] * s;
    (l ? Wb2 : Wb1)[(tap * 64 + co) * 64 + ci] = f2bf(wv);
    if (tap == 0 && ci == 0) {
        const float* cb = l ? cb2 : cb1;
        const float* bb = l ? bb2 : bb1;
        const float* m  = l ? m2  : m1;
        (l ? bias2 : bias1)[co] = s * (cb[co] - m[co]) + bb[co];
    }
}

// ---------------- point MLP + scatter-max ----------------
// one wave per point; lane = output channel
__global__ __launch_bounds__(256) void mlp_scatter(
        const float* __restrict__ points, const float* __restrict__ features,
        const float* __restrict__ w1, const float* __restrict__ b1,
        const float* __restrict__ g1, const float* __restrict__ bb1,
        const float* __restrict__ m1, const float* __restrict__ v1,
        const float* __restrict__ w2, const float* __restrict__ b2,
        float* __restrict__ bev /* (B,H,W,64) fp32, zero-init */) {
    __shared__ float comb[4][132];
    __shared__ float hbuf[4][64];
    const int wid = threadIdx.x >> 6;
    const int lane = threadIdx.x & 63;
    const int pt = blockIdx.x * 4 + wid;

    const float x = points[pt * 3 + 0];
    const float y = points[pt * 3 + 1];
    const float z = points[pt * 3 + 2];
    const bool valid = (x >= -50.f) & (x < 50.f) & (y >= -50.f) & (y < 50.f) &
                       (z >= -3.f) & (z < 5.f);

    if (valid) {
        comb[wid][lane]      = features[pt * CIN + lane];
        comb[wid][64 + lane] = features[pt * CIN + 64 + lane];
        if (lane == 0) {
            comb[wid][128] = (x + 50.f) / 100.f;
            comb[wid][129] = (y + 50.f) / 100.f;
            comb[wid][130] = (z + 3.f) / 8.f;
        }
    }
    __syncthreads();
    if (valid) {
        float acc = b1[lane];
        #pragma unroll 8
        for (int c = 0; c < 131; ++c)
            acc = fmaf(comb[wid][c], w1[c * 64 + lane], acc);
        float hb = (acc - m1[lane]) * rsqrtf(v1[lane] + 1e-5f) * g1[lane] + bb1[lane];
        hbuf[wid][lane] = fmaxf(hb, 0.f);
    }
    __syncthreads();
    if (valid) {
        float acc = b2[lane];
        #pragma unroll 8
        for (int c = 0; c < 64; ++c)
            acc = fmaf(hbuf[wid][c], w2[c * 64 + lane], acc);
        float val = fmaxf(acc, 0.f);
        int col = (int)((x + 50.f) / 0.390625f); col = min(max(col, 0), 255);
        int row = (int)((y + 50.f) / 0.390625f); row = min(max(row, 0), 255);
        int b = pt / NPTS;
        int cell = (b * HH + row) * WW + col;
        atomicMax((int*)bev + cell * 64 + lane, __float_as_int(val));
    }
}

// ---------------- bev fp32 (B,H,W,64) -> padded bf16 (B,258,258,64) interior ----------------
__global__ __launch_bounds__(256) void bev_to_bf16(const float* __restrict__ bev,
                                                   unsigned short* __restrict__ dst) {
    int idx = blockIdx.x * 256 + threadIdx.x;   // one thread per 4 elems
    int e = idx * 4;
    int ci = e & 63;
    int pix = e >> 6;
    int xw = pix & 255;
    int rest = pix >> 8;
    int yw = rest & 255;
    int b = rest >> 8;
    const float4 v = *reinterpret_cast<const float4*>(bev + e);
    ushort4 o;
    o.x = f2bf(v.x); o.y = f2bf(v.y); o.z = f2bf(v.z); o.w = f2bf(v.w);
    int pidx = ((b * HP + yw + 1) * WP + xw + 1) * 64 + ci;
    *reinterpret_cast<ushort4*>(dst + pidx) = o;
}

// ---------------- conv 3x3 64->64, bf16 MFMA implicit GEMM ----------------
// block: 256 thr = 4 waves. tile: 64 pixels (one row segment) x 64 co.
// wave w handles co slice [16w,16w+16), all 64 pixels (4 M-tiles of 16).
// LDS holds 3 input rows x 66 pixels x 64 ci (bf16), pixel stride padded to 72.
#define PSTR 72
template <bool FINAL>
__global__ __launch_bounds__(256) void conv3x3(const unsigned short* __restrict__ Xp,
                                               const unsigned short* __restrict__ Wb,
                                               const float* __restrict__ bias,
                                               void* __restrict__ out) {
    __shared__ unsigned short lds[3 * 66 * PSTR];

    const int bx = blockIdx.x;      // x tile (0..3)
    const int by = blockIdx.y;      // y (0..255)
    const int bz = blockIdx.z;      // batch
    const int tid = threadIdx.x;
    const int x0 = bx * 64;

    // stage 3 rows x 66 px x 64 ci, 16B chunks
    for (int ch = tid; ch < 1584; ch += 256) {
        int flat = ch * 8;
        int r = flat / 4224;            // 66*64
        int rem = flat - r * 4224;
        int p = rem >> 6;
        int ci = rem & 63;
        const uint4 v = *reinterpret_cast<const uint4*>(
            Xp + (((bz * HP + by + r) * WP) + x0 + p) * 64 + ci);
        *reinterpret_cast<uint4*>(&lds[(r * 66 + p) * PSTR + ci]) = v;
    }

    const int wv = tid >> 6;
    const int lane = tid & 63;
    const int n = lane & 15;
    const int q = lane >> 4;

    // preload B fragments: Wb[tap][co][ci], lane(q,n) -> B[kk+8q .. +8][co_base+n]
    short8 bfrag[9][2];
    #pragma unroll
    for (int t = 0; t < 9; ++t)
        #pragma unroll
        for (int kk = 0; kk < 2; ++kk)
            bfrag[t][kk] = *reinterpret_cast<const short8*>(
                Wb + ((t * 64 + wv * 16 + n) * 64 + kk * 32 + q * 8));

    __syncthreads();

    floatx4 acc[4];
    #pragma unroll
    for (int mt = 0; mt < 4; ++mt) acc[mt] = (floatx4){0.f, 0.f, 0.f, 0.f};

    #pragma unroll
    for (int t = 0; t < 9; ++t) {
        const int dy = t / 3, dx = t % 3;
        const int rowbase = dy * 66 * PSTR;
        #pragma unroll
        for (int kk = 0; kk < 2; ++kk) {
            const int cio = kk * 32 + q * 8;
            #pragma unroll
            for (int mt = 0; mt < 4; ++mt) {
                const int p = mt * 16 + n + dx;
                short8 a = *reinterpret_cast<const short8*>(&lds[rowbase + p * PSTR + cio]);
                acc[mt] = __builtin_amdgcn_mfma_f32_16x16x32_bf16(a, bfrag[t][kk], acc[mt], 0, 0, 0);
            }
        }
    }

    // epilogue: D layout col=lane&15 (co), row=q*4+reg (pixel)
    const int co = wv * 16 + n;
    const float bs = bias[co];
    #pragma unroll
    for (int mt = 0; mt < 4; ++mt) {
        #pragma unroll
        for (int r = 0; r < 4; ++r) {
            int px = mt * 16 + q * 4 + r;
            float val = fmaxf(acc[mt][r] + bs, 0.f);
            if (FINAL) {
                ((float*)out)[((bz * 64 + co) * HH + by) * WW + x0 + px] = val;
            } else {
                ((unsigned short*)out)[((bz * HP + by + 1) * WP + (x0 + px + 1)) * 64 + co] = f2bf(val);
            }
        }
    }
}

// ---------------- launch ----------------
extern "C" void kernel_launch(void* const* d_in, const int* in_sizes, int n_in,
                              void* d_out, int out_size, void* d_ws, size_t ws_size,
                              hipStream_t stream) {
    const float* points   = (const float*)d_in[0];
    const float* features = (const float*)d_in[1];
    const float* w1   = (const float*)d_in[2];
    const float* b1   = (const float*)d_in[3];
    const float* bn1g = (const float*)d_in[4];
    const float* bn1b = (const float*)d_in[5];
    const float* bn1m = (const float*)d_in[6];
    const float* bn1v = (const float*)d_in[7];
    const float* w2   = (const float*)d_in[8];
    const float* b2   = (const float*)d_in[9];
    const float* cw1  = (const float*)d_in[10];
    const float* cb1  = (const float*)d_in[11];
    const float* cg1  = (const float*)d_in[12];
    const float* cbb1 = (const float*)d_in[13];
    const float* cm1  = (const float*)d_in[14];
    const float* cv1  = (const float*)d_in[15];
    const float* cw2  = (const float*)d_in[16];
    const float* cb2  = (const float*)d_in[17];
    const float* cg2  = (const float*)d_in[18];
    const float* cbb2 = (const float*)d_in[19];
    const float* cm2  = (const float*)d_in[20];
    const float* cv2  = (const float*)d_in[21];

    float* out = (float*)d_out;
    char* ws = (char*)d_ws;
    unsigned short* buf1 = (unsigned short*)(ws + OFF_BUF1);
    unsigned short* buf2 = (unsigned short*)(ws + OFF_BUF2);
    unsigned short* Wb1  = (unsigned short*)(ws + OFF_WB1);
    unsigned short* Wb2  = (unsigned short*)(ws + OFF_WB2);
    float* bias1 = (float*)(ws + OFF_BIAS1);
    float* bias2 = (float*)(ws + OFF_BIAS2);

    // zero: d_out doubles as fp32 bev scatter buffer (B,H,W,64); pad rings of buf1/buf2
    hipMemsetAsync(d_out, 0, (size_t)BATCH * HH * WW * COUT * 4, stream);
    hipMemsetAsync(buf1, 0, (size_t)SZ_BUF, stream);
    hipMemsetAsync(buf2, 0, (size_t)SZ_BUF, stream);

    prep_weights<<<288, 256, 0, stream>>>(cw1, cb1, cg1, cbb1, cm1, cv1,
                                          cw2, cb2, cg2, cbb2, cm2, cv2,
                                          Wb1, Wb2, bias1, bias2);

    mlp_scatter<<<(BATCH * NPTS) / 4, 256, 0, stream>>>(
        points, features, w1, b1, bn1g, bn1b, bn1m, bn1v, w2, b2, out);

    bev_to_bf16<<<(BATCH * HH * WW * COUT / 4) / 256, 256, 0, stream>>>(out, buf1);

    dim3 cgrid(WW / 64, HH, BATCH);
    conv3x3<false><<<cgrid, 256, 0, stream>>>(buf1, Wb1, bias1, (void*)buf2);
    conv3x3<true><<<cgrid, 256, 0, stream>>>(buf2, Wb2, bias2, (void*)out);
}

// Round 2
// 504.241 us; speedup vs baseline: 2.1202x; 2.1202x over previous
//
#include <hip/hip_runtime.h>

// ---------------- types ----------------
typedef __attribute__((ext_vector_type(8))) short short8;   // 8 bf16 in 4 VGPRs
typedef __attribute__((ext_vector_type(4))) float floatx4;

static __device__ __forceinline__ unsigned short f2bf(float f) {
    unsigned int u = __float_as_uint(f);
    unsigned int r = (u + 0x7FFFu + ((u >> 16) & 1u)) >> 16;   // RNE
    return (unsigned short)r;
}

// ---------------- constants ----------------
#define BATCH 4
#define NPTS 100000
#define CIN 128
#define COUT 64
#define HH 256
#define WW 256
#define HP 258          // padded
#define WP 258

// ws layout (bytes)
#define OFF_BUF1 0
#define SZ_BUF   (BATCH * HP * WP * COUT * 2)          // 34,080,768
#define OFF_BUF2 (OFF_BUF1 + SZ_BUF)
#define OFF_WB1  (OFF_BUF2 + SZ_BUF)                    // 68,161,536
#define SZ_WB    (9 * COUT * COUT * 2)                  // 73,728
#define OFF_WB2  (OFF_WB1 + SZ_WB)
#define OFF_BIAS1 (OFF_WB2 + SZ_WB)                     // 68,308,992
#define OFF_BIAS2 (OFF_BIAS1 + 256)
#define OFF_W1T  (OFF_BIAS2 + 256)                      // 64x160 bf16
#define OFF_B1F  (OFF_W1T + 64 * 160 * 2)
#define OFF_W2T  (OFF_B1F + 256)                        // 64x64 bf16
#define OFF_B2F  (OFF_W2T + 64 * 64 * 2)

// ---------------- prep: fold BN into conv weights, transpose to [tap][co][ci] bf16 ----------------
__global__ void prep_weights(const float* __restrict__ cw1, const float* __restrict__ cb1,
                             const float* __restrict__ g1, const float* __restrict__ bb1,
                             const float* __restrict__ m1, const float* __restrict__ v1,
                             const float* __restrict__ cw2, const float* __restrict__ cb2,
                             const float* __restrict__ g2, const float* __restrict__ bb2,
                             const float* __restrict__ m2, const float* __restrict__ v2,
                             unsigned short* __restrict__ Wb1, unsigned short* __restrict__ Wb2,
                             float* __restrict__ bias1, float* __restrict__ bias2) {
    int idx = blockIdx.x * 256 + threadIdx.x;           // 0 .. 73727
    int l = idx / 36864;
    int r = idx - l * 36864;
    int ci = r & 63;
    int co = (r >> 6) & 63;
    int tap = r >> 12;
    const float* w  = l ? cw2 : cw1;
    const float* g  = l ? g2  : g1;
    const float* v  = l ? v2  : v1;
    float s = g[co] * rsqrtf(v[co] + 1e-5f);
    float wv = w[(co * 64 + ci) * 9 + tap] * s;
    (l ? Wb2 : Wb1)[(tap * 64 + co) * 64 + ci] = f2bf(wv);
    if (tap == 0 && ci == 0) {
        const float* cb = l ? cb2 : cb1;
        const float* bb = l ? bb2 : bb1;
        const float* m  = l ? m2  : m1;
        (l ? bias2 : bias1)[co] = s * (cb[co] - m[co]) + bb[co];
    }
}

// ---------------- prep: MLP weights -> bf16 transposed, BN1 folded ----------------
__global__ void prep_mlp(const float* __restrict__ w1, const float* __restrict__ b1,
                         const float* __restrict__ g, const float* __restrict__ bb,
                         const float* __restrict__ m, const float* __restrict__ v,
                         const float* __restrict__ w2, const float* __restrict__ b2,
                         unsigned short* __restrict__ w1T, float* __restrict__ b1f,
                         unsigned short* __restrict__ w2T, float* __restrict__ b2f) {
    int idx = blockIdx.x * 256 + threadIdx.x;   // 0..10239
    if (idx < 10240) {
        int co = idx / 160, k = idx - co * 160;
        float rs = g[co] * rsqrtf(v[co] + 1e-5f);
        w1T[idx] = f2bf(k < 131 ? w1[k * 64 + co] * rs : 0.f);
        if (k == 0) b1f[co] = (b1[co] - m[co]) * rs + bb[co];
    }
    if (idx < 4096) {
        int co = idx >> 6, k = idx & 63;
        w2T[idx] = f2bf(w2[k * 64 + co]);
        if (k == 0) b2f[co] = b2[co];
    }
}

// ---------------- zero the 1-pixel pad ring of buf1/buf2 ----------------
__global__ void ring_zero(unsigned short* __restrict__ buf1, unsigned short* __restrict__ buf2) {
    int idx = blockIdx.x * 256 + threadIdx.x;       // one uint4 (8 ch) each
    if (idx >= 2 * 4 * 1028 * 8) return;
    int c8 = idx & 7;
    int rest = idx >> 3;
    int p = rest % 1028;
    int rest2 = rest / 1028;
    int b = rest2 & 3;
    int which = rest2 >> 2;
    int x, y;
    if (p < 258)      { y = 0;   x = p; }
    else if (p < 516) { y = 257; x = p - 258; }
    else if (p < 772) { x = 0;   y = p - 516 + 1; }
    else              { x = 257; y = p - 772 + 1; }
    unsigned short* dst = (which ? buf2 : buf1) + (((b * HP + y) * WP + x) * 64 + c8 * 8);
    uint4 z = {0u, 0u, 0u, 0u};
    *reinterpret_cast<uint4*>(dst) = z;
}

// ---------------- point MLP (bf16 MFMA GEMM) + scatter-max, 128 points/block ----------------
#define K1 160
#define ASTR 168
#define HSTR 72
__global__ __launch_bounds__(256) void mlp_gemm_scatter(
        const float* __restrict__ points, const float* __restrict__ features,
        const unsigned short* __restrict__ w1T, const float* __restrict__ b1f,
        const unsigned short* __restrict__ w2T, const float* __restrict__ b2f,
        float* __restrict__ bev /* (B,H,W,64) fp32, zero-init */) {
    __shared__ unsigned short ldsA[128 * ASTR];     // also reused for h (stride HSTR)
    __shared__ int ldsCell[128];

    const int tid = threadIdx.x;
    {   // ---- stage A-tile: combined (features | pos | zeros) as bf16 ----
        const int m = tid >> 1, half = tid & 1;
        const long pt = (long)blockIdx.x * 128 + m;
        const float4* fsrc = reinterpret_cast<const float4*>(features + pt * CIN + half * 64);
        unsigned short* arow = &ldsA[m * ASTR + half * 64];
        #pragma unroll
        for (int i = 0; i < 16; ++i) {
            float4 f = fsrc[i];
            ushort4 o;
            o.x = f2bf(f.x); o.y = f2bf(f.y); o.z = f2bf(f.z); o.w = f2bf(f.w);
            *reinterpret_cast<ushort4*>(arow + i * 4) = o;
        }
        if (half) {
            float x = points[pt * 3 + 0];
            float y = points[pt * 3 + 1];
            float z = points[pt * 3 + 2];
            bool valid = (x >= -50.f) & (x < 50.f) & (y >= -50.f) & (y < 50.f) &
                         (z >= -3.f) & (z < 5.f);
            unsigned short tail[32];
            tail[0] = f2bf((x + 50.f) * 0.01f);
            tail[1] = f2bf((y + 50.f) * 0.01f);
            tail[2] = f2bf((z + 3.f) * 0.125f);
            #pragma unroll
            for (int i = 3; i < 32; ++i) tail[i] = 0;
            #pragma unroll
            for (int i = 0; i < 8; ++i)
                *reinterpret_cast<ushort4*>(&ldsA[m * ASTR + 128 + i * 4]) =
                    *reinterpret_cast<ushort4*>(&tail[i * 4]);
            int cell = -1;
            if (valid) {
                int col = (int)((x + 50.f) / 0.390625f); col = min(max(col, 0), 255);
                int row = (int)((y + 50.f) / 0.390625f); row = min(max(row, 0), 255);
                int b = pt >= 300000 ? 3 : (pt >= 200000 ? 2 : (pt >= 100000 ? 1 : 0));
                cell = (b * HH + row) * WW + col;
            }
            ldsCell[m] = cell;
        }
    }
    __syncthreads();

    const int w = tid >> 6, lane = tid & 63, n = lane & 15, q = lane >> 4;

    // ---- GEMM1: (128 x 160) x (160 x 64) ----
    floatx4 acc[2][4];
    #pragma unroll
    for (int mt = 0; mt < 2; ++mt)
        #pragma unroll
        for (int nt = 0; nt < 4; ++nt) acc[mt][nt] = (floatx4){0.f, 0.f, 0.f, 0.f};

    #pragma unroll
    for (int ks = 0; ks < 5; ++ks) {
        short8 bf[4];
        #pragma unroll
        for (int nt = 0; nt < 4; ++nt)
            bf[nt] = *reinterpret_cast<const short8*>(w1T + (nt * 16 + n) * K1 + ks * 32 + q * 8);
        #pragma unroll
        for (int mt = 0; mt < 2; ++mt) {
            short8 a = *reinterpret_cast<const short8*>(
                &ldsA[(w * 32 + mt * 16 + n) * ASTR + ks * 32 + q * 8]);
            #pragma unroll
            for (int nt = 0; nt < 4; ++nt)
                acc[mt][nt] = __builtin_amdgcn_mfma_f32_16x16x32_bf16(a, bf[nt], acc[mt][nt], 0, 0, 0);
        }
    }

    float bs1[4];
    #pragma unroll
    for (int nt = 0; nt < 4; ++nt) bs1[nt] = b1f[nt * 16 + n];

    __syncthreads();    // all A reads done before overwriting with h

    // ---- ReLU + write h (bf16) back to LDS in A-layout ----
    #pragma unroll
    for (int mt = 0; mt < 2; ++mt)
        #pragma unroll
        for (int nt = 0; nt < 4; ++nt)
            #pragma unroll
            for (int r = 0; r < 4; ++r) {
                int mm = w * 32 + mt * 16 + q * 4 + r;
                float hv = fmaxf(acc[mt][nt][r] + bs1[nt], 0.f);
                ldsA[mm * HSTR + nt * 16 + n] = f2bf(hv);
            }
    __syncthreads();

    // ---- GEMM2: (128 x 64) x (64 x 64) ----
    floatx4 acc2[2][4];
    #pragma unroll
    for (int mt = 0; mt < 2; ++mt)
        #pragma unroll
        for (int nt = 0; nt < 4; ++nt) acc2[mt][nt] = (floatx4){0.f, 0.f, 0.f, 0.f};

    #pragma unroll
    for (int ks = 0; ks < 2; ++ks) {
        short8 bf[4];
        #pragma unroll
        for (int nt = 0; nt < 4; ++nt)
            bf[nt] = *reinterpret_cast<const short8*>(w2T + (nt * 16 + n) * 64 + ks * 32 + q * 8);
        #pragma unroll
        for (int mt = 0; mt < 2; ++mt) {
            short8 a = *reinterpret_cast<const short8*>(
                &ldsA[(w * 32 + mt * 16 + n) * HSTR + ks * 32 + q * 8]);
            #pragma unroll
            for (int nt = 0; nt < 4; ++nt)
                acc2[mt][nt] = __builtin_amdgcn_mfma_f32_16x16x32_bf16(a, bf[nt], acc2[mt][nt], 0, 0, 0);
        }
    }

    float bs2[4];
    #pragma unroll
    for (int nt = 0; nt < 4; ++nt) bs2[nt] = b2f[nt * 16 + n];

    // ---- epilogue: clamp + scatter atomicMax ----
    #pragma unroll
    for (int mt = 0; mt < 2; ++mt)
        #pragma unroll
        for (int r = 0; r < 4; ++r) {
            int mm = w * 32 + mt * 16 + q * 4 + r;
            int cell = ldsCell[mm];
            if (cell >= 0) {
                int* base = (int*)bev + cell * 64;
                #pragma unroll
                for (int nt = 0; nt < 4; ++nt) {
                    float val = fmaxf(acc2[mt][nt][r] + bs2[nt], 0.f);
                    atomicMax(base + nt * 16 + n, __float_as_int(val));
                }
            }
        }
}

// ---------------- bev fp32 (B,H,W,64) -> padded bf16 (B,258,258,64) interior ----------------
__global__ __launch_bounds__(256) void bev_to_bf16(const float* __restrict__ bev,
                                                   unsigned short* __restrict__ dst) {
    int idx = blockIdx.x * 256 + threadIdx.x;   // one thread per 4 elems
    int e = idx * 4;
    int ci = e & 63;
    int pix = e >> 6;
    int xw = pix & 255;
    int rest = pix >> 8;
    int yw = rest & 255;
    int b = rest >> 8;
    const float4 v = *reinterpret_cast<const float4*>(bev + e);
    ushort4 o;
    o.x = f2bf(v.x); o.y = f2bf(v.y); o.z = f2bf(v.z); o.w = f2bf(v.w);
    int pidx = ((b * HP + yw + 1) * WP + xw + 1) * 64 + ci;
    *reinterpret_cast<ushort4*>(dst + pidx) = o;
}

// ---------------- conv 3x3 64->64, bf16 MFMA implicit GEMM ----------------
#define PSTR 72
template <bool FINAL>
__global__ __launch_bounds__(256) void conv3x3(const unsigned short* __restrict__ Xp,
                                               const unsigned short* __restrict__ Wb,
                                               const float* __restrict__ bias,
                                               void* __restrict__ out) {
    __shared__ unsigned short lds[3 * 66 * PSTR];

    const int bx = blockIdx.x;      // x tile (0..3)
    const int by = blockIdx.y;      // y (0..255)
    const int bz = blockIdx.z;      // batch
    const int tid = threadIdx.x;
    const int x0 = bx * 64;

    // stage 3 rows x 66 px x 64 ci, 16B chunks
    for (int ch = tid; ch < 1584; ch += 256) {
        int flat = ch * 8;
        int r = flat / 4224;            // 66*64
        int rem = flat - r * 4224;
        int p = rem >> 6;
        int ci = rem & 63;
        const uint4 v = *reinterpret_cast<const uint4*>(
            Xp + (((bz * HP + by + r) * WP) + x0 + p) * 64 + ci);
        *reinterpret_cast<uint4*>(&lds[(r * 66 + p) * PSTR + ci]) = v;
    }

    const int wv = tid >> 6;
    const int lane = tid & 63;
    const int n = lane & 15;
    const int q = lane >> 4;

    // preload B fragments: Wb[tap][co][ci]
    short8 bfrag[9][2];
    #pragma unroll
    for (int t = 0; t < 9; ++t)
        #pragma unroll
        for (int kk = 0; kk < 2; ++kk)
            bfrag[t][kk] = *reinterpret_cast<const short8*>(
                Wb + ((t * 64 + wv * 16 + n) * 64 + kk * 32 + q * 8));

    __syncthreads();

    floatx4 acc[4];
    #pragma unroll
    for (int mt = 0; mt < 4; ++mt) acc[mt] = (floatx4){0.f, 0.f, 0.f, 0.f};

    #pragma unroll
    for (int t = 0; t < 9; ++t) {
        const int dy = t / 3, dx = t % 3;
        const int rowbase = dy * 66 * PSTR;
        #pragma unroll
        for (int kk = 0; kk < 2; ++kk) {
            const int cio = kk * 32 + q * 8;
            #pragma unroll
            for (int mt = 0; mt < 4; ++mt) {
                const int p = mt * 16 + n + dx;
                short8 a = *reinterpret_cast<const short8*>(&lds[rowbase + p * PSTR + cio]);
                acc[mt] = __builtin_amdgcn_mfma_f32_16x16x32_bf16(a, bfrag[t][kk], acc[mt], 0, 0, 0);
            }
        }
    }

    // epilogue: D layout col=lane&15 (co), row=q*4+reg (pixel)
    const int co = wv * 16 + n;
    const float bs = bias[co];
    #pragma unroll
    for (int mt = 0; mt < 4; ++mt) {
        #pragma unroll
        for (int r = 0; r < 4; ++r) {
            int px = mt * 16 + q * 4 + r;
            float val = fmaxf(acc[mt][r] + bs, 0.f);
            if (FINAL) {
                ((float*)out)[((bz * 64 + co) * HH + by) * WW + x0 + px] = val;
            } else {
                ((unsigned short*)out)[((bz * HP + by + 1) * WP + (x0 + px + 1)) * 64 + co] = f2bf(val);
            }
        }
    }
}

// ---------------- launch ----------------
extern "C" void kernel_launch(void* const* d_in, const int* in_sizes, int n_in,
                              void* d_out, int out_size, void* d_ws, size_t ws_size,
                              hipStream_t stream) {
    const float* points   = (const float*)d_in[0];
    const float* features = (const float*)d_in[1];
    const float* w1   = (const float*)d_in[2];
    const float* b1   = (const float*)d_in[3];
    const float* bn1g = (const float*)d_in[4];
    const float* bn1b = (const float*)d_in[5];
    const float* bn1m = (const float*)d_in[6];
    const float* bn1v = (const float*)d_in[7];
    const float* w2   = (const float*)d_in[8];
    const float* b2   = (const float*)d_in[9];
    const float* cw1  = (const float*)d_in[10];
    const float* cb1  = (const float*)d_in[11];
    const float* cg1  = (const float*)d_in[12];
    const float* cbb1 = (const float*)d_in[13];
    const float* cm1  = (const float*)d_in[14];
    const float* cv1  = (const float*)d_in[15];
    const float* cw2  = (const float*)d_in[16];
    const float* cb2  = (const float*)d_in[17];
    const float* cg2  = (const float*)d_in[18];
    const float* cbb2 = (const float*)d_in[19];
    const float* cm2  = (const float*)d_in[20];
    const float* cv2  = (const float*)d_in[21];

    float* out = (float*)d_out;
    char* ws = (char*)d_ws;
    unsigned short* buf1 = (unsigned short*)(ws + OFF_BUF1);
    unsigned short* buf2 = (unsigned short*)(ws + OFF_BUF2);
    unsigned short* Wb1  = (unsigned short*)(ws + OFF_WB1);
    unsigned short* Wb2  = (unsigned short*)(ws + OFF_WB2);
    float* bias1 = (float*)(ws + OFF_BIAS1);
    float* bias2 = (float*)(ws + OFF_BIAS2);
    unsigned short* w1T = (unsigned short*)(ws + OFF_W1T);
    float* b1f = (float*)(ws + OFF_B1F);
    unsigned short* w2T = (unsigned short*)(ws + OFF_W2T);
    float* b2f = (float*)(ws + OFF_B2F);

    // d_out doubles as the fp32 bev scatter buffer (B,H,W,64) — must be zero
    hipMemsetAsync(d_out, 0, (size_t)BATCH * HH * WW * COUT * 4, stream);
    ring_zero<<<(2 * 4 * 1028 * 8 + 255) / 256, 256, 0, stream>>>(buf1, buf2);

    prep_weights<<<288, 256, 0, stream>>>(cw1, cb1, cg1, cbb1, cm1, cv1,
                                          cw2, cb2, cg2, cbb2, cm2, cv2,
                                          Wb1, Wb2, bias1, bias2);
    prep_mlp<<<40, 256, 0, stream>>>(w1, b1, bn1g, bn1b, bn1m, bn1v, w2, b2,
                                     w1T, b1f, w2T, b2f);

    mlp_gemm_scatter<<<(BATCH * NPTS) / 128, 256, 0, stream>>>(
        points, features, w1T, b1f, w2T, b2f, out);

    bev_to_bf16<<<(BATCH * HH * WW * COUT / 4) / 256, 256, 0, stream>>>(out, buf1);

    dim3 cgrid(WW / 64, HH, BATCH);
    conv3x3<false><<<cgrid, 256, 0, stream>>>(buf1, Wb1, bias1, (void*)buf2);
    conv3x3<true><<<cgrid, 256, 0, stream>>>(buf2, Wb2, bias2, (void*)out);
}

// Round 3
// 497.963 us; speedup vs baseline: 2.1470x; 1.0126x over previous
//
#include <hip/hip_runtime.h>
#include <hip/hip_bf16.h>

// ---------------- types ----------------
typedef __attribute__((ext_vector_type(8))) short short8;   // 8 bf16 in 4 VGPRs
typedef __attribute__((ext_vector_type(4))) float floatx4;

static __device__ __forceinline__ unsigned short f2bf(float f) {
    unsigned int u = __float_as_uint(f);
    unsigned int r = (u + 0x7FFFu + ((u >> 16) & 1u)) >> 16;   // RNE
    return (unsigned short)r;
}

// pack 8 consecutive fp32 -> 8 bf16 (RNE, packed cvt)
static __device__ __forceinline__ short8 cvt8(const float* __restrict__ p) {
    const float4 f0 = *reinterpret_cast<const float4*>(p);
    const float4 f1 = *reinterpret_cast<const float4*>(p + 4);
    union { short8 s; __hip_bfloat162 h[4]; } u;
    u.h[0] = __float22bfloat162_rn(make_float2(f0.x, f0.y));
    u.h[1] = __float22bfloat162_rn(make_float2(f0.z, f0.w));
    u.h[2] = __float22bfloat162_rn(make_float2(f1.x, f1.y));
    u.h[3] = __float22bfloat162_rn(make_float2(f1.z, f1.w));
    return u.s;
}
static __device__ __forceinline__ uint4 cvt8u(const float* __restrict__ p) {
    const float4 f0 = *reinterpret_cast<const float4*>(p);
    const float4 f1 = *reinterpret_cast<const float4*>(p + 4);
    union { uint4 u; __hip_bfloat162 h[4]; } w;
    w.h[0] = __float22bfloat162_rn(make_float2(f0.x, f0.y));
    w.h[1] = __float22bfloat162_rn(make_float2(f0.z, f0.w));
    w.h[2] = __float22bfloat162_rn(make_float2(f1.x, f1.y));
    w.h[3] = __float22bfloat162_rn(make_float2(f1.z, f1.w));
    return w.u;
}

// ---------------- constants ----------------
#define BATCH 4
#define NPTS 100000
#define CIN 128
#define COUT 64
#define HH 256
#define WW 256
#define HP 258          // padded
#define WP 258

// ws layout (bytes)
#define OFF_BUF2 0
#define SZ_BUF   (BATCH * HP * WP * COUT * 2)           // 34,080,768
#define OFF_WB1  (OFF_BUF2 + SZ_BUF)
#define SZ_WB    (9 * COUT * COUT * 2)                  // 73,728
#define OFF_WB2  (OFF_WB1 + SZ_WB)
#define OFF_BIAS1 (OFF_WB2 + SZ_WB)
#define OFF_BIAS2 (OFF_BIAS1 + 256)
#define OFF_W1T  (OFF_BIAS2 + 256)                      // 64x128 bf16
#define OFF_W1POS (OFF_W1T + 64 * 128 * 2)              // 3x64 fp32
#define OFF_B1F  (OFF_W1POS + 768)
#define OFF_W2T  (OFF_B1F + 256)                        // 64x64 bf16
#define OFF_B2F  (OFF_W2T + 64 * 64 * 2)

// ---------------- prep: fold BN into conv weights, transpose to [tap][co][ci] bf16 ----------------
__global__ void prep_weights(const float* __restrict__ cw1, const float* __restrict__ cb1,
                             const float* __restrict__ g1, const float* __restrict__ bb1,
                             const float* __restrict__ m1, const float* __restrict__ v1,
                             const float* __restrict__ cw2, const float* __restrict__ cb2,
                             const float* __restrict__ g2, const float* __restrict__ bb2,
                             const float* __restrict__ m2, const float* __restrict__ v2,
                             unsigned short* __restrict__ Wb1, unsigned short* __restrict__ Wb2,
                             float* __restrict__ bias1, float* __restrict__ bias2) {
    int idx = blockIdx.x * 256 + threadIdx.x;           // 0 .. 73727
    int l = idx / 36864;
    int r = idx - l * 36864;
    int ci = r & 63;
    int co = (r >> 6) & 63;
    int tap = r >> 12;
    const float* w  = l ? cw2 : cw1;
    const float* g  = l ? g2  : g1;
    const float* v  = l ? v2  : v1;
    float s = g[co] * rsqrtf(v[co] + 1e-5f);
    float wv = w[(co * 64 + ci) * 9 + tap] * s;
    (l ? Wb2 : Wb1)[(tap * 64 + co) * 64 + ci] = f2bf(wv);
    if (tap == 0 && ci == 0) {
        const float* cb = l ? cb2 : cb1;
        const float* bb = l ? bb2 : bb1;
        const float* m  = l ? m2  : m1;
        (l ? bias2 : bias1)[co] = s * (cb[co] - m[co]) + bb[co];
    }
}

// ---------------- prep: MLP weights -> bf16 transposed (K=128), pos rows fp32, BN1 folded ----------------
__global__ void prep_mlp(const float* __restrict__ w1, const float* __restrict__ b1,
                         const float* __restrict__ g, const float* __restrict__ bb,
                         const float* __restrict__ m, const float* __restrict__ v,
                         const float* __restrict__ w2, const float* __restrict__ b2,
                         unsigned short* __restrict__ w1T, float* __restrict__ w1pos,
                         float* __restrict__ b1f,
                         unsigned short* __restrict__ w2T, float* __restrict__ b2f) {
    int idx = blockIdx.x * 256 + threadIdx.x;   // 0..8191
    if (idx < 8192) {
        int co = idx >> 7, k = idx & 127;
        float rs = g[co] * rsqrtf(v[co] + 1e-5f);
        w1T[idx] = f2bf(w1[k * 64 + co] * rs);
        if (k < 3) w1pos[k * 64 + co] = w1[(128 + k) * 64 + co] * rs;
        if (k == 0) b1f[co] = (b1[co] - m[co]) * rs + bb[co];
    }
    if (idx < 4096) {
        int co = idx >> 6, k = idx & 63;
        w2T[idx] = f2bf(w2[k * 64 + co]);
        if (k == 0) b2f[co] = b2[co];
    }
}

// ---------------- zero the 1-pixel pad ring of buf2 ----------------
__global__ void ring_zero(unsigned short* __restrict__ buf2) {
    int idx = blockIdx.x * 256 + threadIdx.x;       // one uint4 (8 ch) each
    if (idx >= 4 * 1028 * 8) return;
    int c8 = idx & 7;
    int rest = idx >> 3;
    int p = rest % 1028;
    int b = rest / 1028;
    int x, y;
    if (p < 258)      { y = 0;   x = p; }
    else if (p < 516) { y = 257; x = p - 258; }
    else if (p < 772) { x = 0;   y = p - 516 + 1; }
    else              { x = 257; y = p - 772 + 1; }
    unsigned short* dst = buf2 + (((b * HP + y) * WP + x) * 64 + c8 * 8);
    uint4 z = {0u, 0u, 0u, 0u};
    *reinterpret_cast<uint4*>(dst) = z;
}

// ---------------- point MLP (bf16 MFMA, A-frags direct from global) + scatter-max ----------------
// 128 points/block, 4 waves; wave w owns points [w*32, w*32+32) as 2 M-tiles.
#define HSTR 72
__global__ __launch_bounds__(256) void mlp_gemm_scatter(
        const float* __restrict__ points, const float* __restrict__ features,
        const unsigned short* __restrict__ w1T, const float* __restrict__ w1pos,
        const float* __restrict__ b1f,
        const unsigned short* __restrict__ w2T, const float* __restrict__ b2f,
        float* __restrict__ bev /* (B,H,W,64) fp32, zero-init */) {
    __shared__ unsigned short ldsH[128 * HSTR];     // h, bf16, A-layout
    __shared__ float4 ldsPos[128];                  // posx,posy,posz, cell(int bits)

    const int tid = threadIdx.x;
    const long pt0 = (long)blockIdx.x * 128;

    if (tid < 128) {
        const long pt = pt0 + tid;
        const float x = points[pt * 3 + 0];
        const float y = points[pt * 3 + 1];
        const float z = points[pt * 3 + 2];
        const bool valid = (x >= -50.f) & (x < 50.f) & (y >= -50.f) & (y < 50.f) &
                           (z >= -3.f) & (z < 5.f);
        int cell = -1;
        if (valid) {
            int col = (int)((x + 50.f) / 0.390625f); col = min(max(col, 0), 255);
            int row = (int)((y + 50.f) / 0.390625f); row = min(max(row, 0), 255);
            int b = pt >= 300000 ? 3 : (pt >= 200000 ? 2 : (pt >= 100000 ? 1 : 0));
            cell = (b * HH + row) * WW + col;
        }
        float4 v;
        v.x = (x + 50.f) * 0.01f;
        v.y = (y + 50.f) * 0.01f;
        v.z = (z + 3.f) * 0.125f;
        v.w = __int_as_float(cell);
        ldsPos[tid] = v;
    }
    __syncthreads();

    const int w = tid >> 6, lane = tid & 63, n = lane & 15, q = lane >> 4;
    const int m0 = w * 32;

    // ---- GEMM1: (128 x 128) x (128 x 64), A direct from global fp32 ----
    floatx4 acc[2][4];
    #pragma unroll
    for (int mt = 0; mt < 2; ++mt)
        #pragma unroll
        for (int nt = 0; nt < 4; ++nt) acc[mt][nt] = (floatx4){0.f, 0.f, 0.f, 0.f};

    #pragma unroll
    for (int ks = 0; ks < 4; ++ks) {
        short8 bf[4];
        #pragma unroll
        for (int nt = 0; nt < 4; ++nt)
            bf[nt] = *reinterpret_cast<const short8*>(w1T + (nt * 16 + n) * 128 + ks * 32 + q * 8);
        #pragma unroll
        for (int mt = 0; mt < 2; ++mt) {
            short8 a = cvt8(features + (pt0 + m0 + mt * 16 + n) * CIN + ks * 32 + q * 8);
            #pragma unroll
            for (int nt = 0; nt < 4; ++nt)
                acc[mt][nt] = __builtin_amdgcn_mfma_f32_16x16x32_bf16(a, bf[nt], acc[mt][nt], 0, 0, 0);
        }
    }

    // pos rank-3 update weights + bias (fp32, exact)
    float w1p[3][4], bs1[4];
    #pragma unroll
    for (int nt = 0; nt < 4; ++nt) {
        bs1[nt] = b1f[nt * 16 + n];
        #pragma unroll
        for (int j = 0; j < 3; ++j) w1p[j][nt] = w1pos[j * 64 + nt * 16 + n];
    }

    // ---- h = relu(acc + bias + pos·w1pos) -> LDS (bf16, A-layout) ----
    #pragma unroll
    for (int mt = 0; mt < 2; ++mt)
        #pragma unroll
        for (int r = 0; r < 4; ++r) {
            const int mm = m0 + mt * 16 + q * 4 + r;
            const float4 pos = ldsPos[mm];
            #pragma unroll
            for (int nt = 0; nt < 4; ++nt) {
                float hv = acc[mt][nt][r] + bs1[nt]
                         + pos.x * w1p[0][nt] + pos.y * w1p[1][nt] + pos.z * w1p[2][nt];
                ldsH[mm * HSTR + nt * 16 + n] = f2bf(fmaxf(hv, 0.f));
            }
        }
    __syncthreads();

    // ---- GEMM2: (128 x 64) x (64 x 64) ----
    floatx4 acc2[2][4];
    #pragma unroll
    for (int mt = 0; mt < 2; ++mt)
        #pragma unroll
        for (int nt = 0; nt < 4; ++nt) acc2[mt][nt] = (floatx4){0.f, 0.f, 0.f, 0.f};

    #pragma unroll
    for (int ks = 0; ks < 2; ++ks) {
        short8 bf[4];
        #pragma unroll
        for (int nt = 0; nt < 4; ++nt)
            bf[nt] = *reinterpret_cast<const short8*>(w2T + (nt * 16 + n) * 64 + ks * 32 + q * 8);
        #pragma unroll
        for (int mt = 0; mt < 2; ++mt) {
            short8 a = *reinterpret_cast<const short8*>(
                &ldsH[(m0 + mt * 16 + n) * HSTR + ks * 32 + q * 8]);
            #pragma unroll
            for (int nt = 0; nt < 4; ++nt)
                acc2[mt][nt] = __builtin_amdgcn_mfma_f32_16x16x32_bf16(a, bf[nt], acc2[mt][nt], 0, 0, 0);
        }
    }

    float bs2[4];
    #pragma unroll
    for (int nt = 0; nt < 4; ++nt) bs2[nt] = b2f[nt * 16 + n];

    // ---- epilogue: clamp + scatter atomicMax (floats >=0 order as ints) ----
    #pragma unroll
    for (int mt = 0; mt < 2; ++mt)
        #pragma unroll
        for (int r = 0; r < 4; ++r) {
            const int mm = m0 + mt * 16 + q * 4 + r;
            const int cell = __float_as_int(ldsPos[mm].w);
            if (cell >= 0) {
                int* base = (int*)bev + (long)cell * 64;
                #pragma unroll
                for (int nt = 0; nt < 4; ++nt) {
                    float val = fmaxf(acc2[mt][nt][r] + bs2[nt], 0.f);
                    atomicMax(base + nt * 16 + n, __float_as_int(val));
                }
            }
        }
}

// ---------------- conv 3x3 64->64, bf16 MFMA implicit GEMM ----------------
// SRCF32: stage from fp32 NHWC bev (B,256,256,64) with boundary predication.
// else: stage from padded bf16 (B,258,258,64).
#define PSTR 72
template <bool FINAL, bool SRCF32>
__global__ __launch_bounds__(256) void conv3x3(const void* __restrict__ Xsrc,
                                               const unsigned short* __restrict__ Wb,
                                               const float* __restrict__ bias,
                                               void* __restrict__ out) {
    __shared__ unsigned short lds[3 * 66 * PSTR];

    const int bx = blockIdx.x;      // x tile (0..3)
    const int by = blockIdx.y;      // y (0..255)
    const int bz = blockIdx.z;      // batch
    const int tid = threadIdx.x;
    const int x0 = bx * 64;

    // stage 3 rows x 66 px x 64 ci (bf16), 16B chunks
    for (int ch = tid; ch < 1584; ch += 256) {
        int flat = ch * 8;
        int r = flat / 4224;            // 66*64
        int rem = flat - r * 4224;
        int p = rem >> 6;
        int ci = rem & 63;
        uint4 v;
        if (SRCF32) {
            int gy = by + r - 1;
            int gx = x0 + p - 1;
            if (gy >= 0 && gy < HH && gx >= 0 && gx < WW) {
                v = cvt8u((const float*)Xsrc + (((bz * HH + gy) * WW) + gx) * 64 + ci);
            } else {
                v = (uint4){0u, 0u, 0u, 0u};
            }
        } else {
            v = *reinterpret_cast<const uint4*>(
                (const unsigned short*)Xsrc + (((bz * HP + by + r) * WP) + x0 + p) * 64 + ci);
        }
        *reinterpret_cast<uint4*>(&lds[(r * 66 + p) * PSTR + ci]) = v;
    }

    const int wv = tid >> 6;
    const int lane = tid & 63;
    const int n = lane & 15;
    const int q = lane >> 4;

    // preload B fragments: Wb[tap][co][ci]
    short8 bfrag[9][2];
    #pragma unroll
    for (int t = 0; t < 9; ++t)
        #pragma unroll
        for (int kk = 0; kk < 2; ++kk)
            bfrag[t][kk] = *reinterpret_cast<const short8*>(
                Wb + ((t * 64 + wv * 16 + n) * 64 + kk * 32 + q * 8));

    __syncthreads();

    floatx4 acc[4];
    #pragma unroll
    for (int mt = 0; mt < 4; ++mt) acc[mt] = (floatx4){0.f, 0.f, 0.f, 0.f};

    #pragma unroll
    for (int t = 0; t < 9; ++t) {
        const int dy = t / 3, dx = t % 3;
        const int rowbase = dy * 66 * PSTR;
        #pragma unroll
        for (int kk = 0; kk < 2; ++kk) {
            const int cio = kk * 32 + q * 8;
            #pragma unroll
            for (int mt = 0; mt < 4; ++mt) {
                const int p = mt * 16 + n + dx;
                short8 a = *reinterpret_cast<const short8*>(&lds[rowbase + p * PSTR + cio]);
                acc[mt] = __builtin_amdgcn_mfma_f32_16x16x32_bf16(a, bfrag[t][kk], acc[mt], 0, 0, 0);
            }
        }
    }

    // epilogue: D layout col=lane&15 (co), row=q*4+reg (pixel)
    const int co = wv * 16 + n;
    const float bs = bias[co];
    #pragma unroll
    for (int mt = 0; mt < 4; ++mt) {
        #pragma unroll
        for (int r = 0; r < 4; ++r) {
            int px = mt * 16 + q * 4 + r;
            float val = fmaxf(acc[mt][r] + bs, 0.f);
            if (FINAL) {
                ((float*)out)[((bz * 64 + co) * HH + by) * WW + x0 + px] = val;
            } else {
                ((unsigned short*)out)[((bz * HP + by + 1) * WP + (x0 + px + 1)) * 64 + co] = f2bf(val);
            }
        }
    }
}

// ---------------- launch ----------------
extern "C" void kernel_launch(void* const* d_in, const int* in_sizes, int n_in,
                              void* d_out, int out_size, void* d_ws, size_t ws_size,
                              hipStream_t stream) {
    const float* points   = (const float*)d_in[0];
    const float* features = (const float*)d_in[1];
    const float* w1   = (const float*)d_in[2];
    const float* b1   = (const float*)d_in[3];
    const float* bn1g = (const float*)d_in[4];
    const float* bn1b = (const float*)d_in[5];
    const float* bn1m = (const float*)d_in[6];
    const float* bn1v = (const float*)d_in[7];
    const float* w2   = (const float*)d_in[8];
    const float* b2   = (const float*)d_in[9];
    const float* cw1  = (const float*)d_in[10];
    const float* cb1  = (const float*)d_in[11];
    const float* cg1  = (const float*)d_in[12];
    const float* cbb1 = (const float*)d_in[13];
    const float* cm1  = (const float*)d_in[14];
    const float* cv1  = (const float*)d_in[15];
    const float* cw2  = (const float*)d_in[16];
    const float* cb2  = (const float*)d_in[17];
    const float* cg2  = (const float*)d_in[18];
    const float* cbb2 = (const float*)d_in[19];
    const float* cm2  = (const float*)d_in[20];
    const float* cv2  = (const float*)d_in[21];

    float* out = (float*)d_out;
    char* ws = (char*)d_ws;
    unsigned short* buf2 = (unsigned short*)(ws + OFF_BUF2);
    unsigned short* Wb1  = (unsigned short*)(ws + OFF_WB1);
    unsigned short* Wb2  = (unsigned short*)(ws + OFF_WB2);
    float* bias1 = (float*)(ws + OFF_BIAS1);
    float* bias2 = (float*)(ws + OFF_BIAS2);
    unsigned short* w1T = (unsigned short*)(ws + OFF_W1T);
    float* w1pos = (float*)(ws + OFF_W1POS);
    float* b1f = (float*)(ws + OFF_B1F);
    unsigned short* w2T = (unsigned short*)(ws + OFF_W2T);
    float* b2f = (float*)(ws + OFF_B2F);

    // d_out doubles as the fp32 bev scatter buffer (B,H,W,64) — must be zero
    hipMemsetAsync(d_out, 0, (size_t)BATCH * HH * WW * COUT * 4, stream);
    ring_zero<<<(4 * 1028 * 8 + 255) / 256, 256, 0, stream>>>(buf2);

    prep_weights<<<288, 256, 0, stream>>>(cw1, cb1, cg1, cbb1, cm1, cv1,
                                          cw2, cb2, cg2, cbb2, cm2, cv2,
                                          Wb1, Wb2, bias1, bias2);
    prep_mlp<<<32, 256, 0, stream>>>(w1, b1, bn1g, bn1b, bn1m, bn1v, w2, b2,
                                     w1T, w1pos, b1f, w2T, b2f);

    mlp_gemm_scatter<<<(BATCH * NPTS) / 128, 256, 0, stream>>>(
        points, features, w1T, w1pos, b1f, w2T, b2f, out);

    dim3 cgrid(WW / 64, HH, BATCH);
    conv3x3<false, true><<<cgrid, 256, 0, stream>>>((const void*)out, Wb1, bias1, (void*)buf2);
    conv3x3<true, false><<<cgrid, 256, 0, stream>>>((const void*)buf2, Wb2, bias2, (void*)out);
}

// Round 4
// 490.745 us; speedup vs baseline: 2.1785x; 1.0147x over previous
//
#include <hip/hip_runtime.h>
#include <hip/hip_bf16.h>

// ---------------- types ----------------
typedef __attribute__((ext_vector_type(8))) short short8;   // 8 bf16 in 4 VGPRs
typedef __attribute__((ext_vector_type(4))) float floatx4;

static __device__ __forceinline__ unsigned short f2bf(float f) {
    unsigned int u = __float_as_uint(f);
    unsigned int r = (u + 0x7FFFu + ((u >> 16) & 1u)) >> 16;   // RNE
    return (unsigned short)r;
}

// pack 8 consecutive fp32 -> 8 bf16 (RNE, packed cvt)
static __device__ __forceinline__ short8 cvt8(const float* __restrict__ p) {
    const float4 f0 = *reinterpret_cast<const float4*>(p);
    const float4 f1 = *reinterpret_cast<const float4*>(p + 4);
    union { short8 s; __hip_bfloat162 h[4]; } u;
    u.h[0] = __float22bfloat162_rn(make_float2(f0.x, f0.y));
    u.h[1] = __float22bfloat162_rn(make_float2(f0.z, f0.w));
    u.h[2] = __float22bfloat162_rn(make_float2(f1.x, f1.y));
    u.h[3] = __float22bfloat162_rn(make_float2(f1.z, f1.w));
    return u.s;
}
static __device__ __forceinline__ uint4 cvt8u(const float* __restrict__ p) {
    const float4 f0 = *reinterpret_cast<const float4*>(p);
    const float4 f1 = *reinterpret_cast<const float4*>(p + 4);
    union { uint4 u; __hip_bfloat162 h[4]; } w;
    w.h[0] = __float22bfloat162_rn(make_float2(f0.x, f0.y));
    w.h[1] = __float22bfloat162_rn(make_float2(f0.z, f0.w));
    w.h[2] = __float22bfloat162_rn(make_float2(f1.x, f1.y));
    w.h[3] = __float22bfloat162_rn(make_float2(f1.z, f1.w));
    return w.u;
}

// ---------------- constants ----------------
#define BATCH 4
#define NPTS 100000
#define CIN 128
#define COUT 64
#define HH 256
#define WW 256
#define HP 258          // padded
#define WP 258

// ws layout (bytes)
#define OFF_BUF2 0
#define SZ_BUF   (BATCH * HP * WP * COUT * 2)           // 34,080,768
#define OFF_WB1  (OFF_BUF2 + SZ_BUF)
#define SZ_WB    (9 * COUT * COUT * 2)                  // 73,728
#define OFF_WB2  (OFF_WB1 + SZ_WB)
#define OFF_BIAS1 (OFF_WB2 + SZ_WB)
#define OFF_BIAS2 (OFF_BIAS1 + 256)
#define OFF_W1T  (OFF_BIAS2 + 256)                      // 64x128 bf16
#define OFF_W1POS (OFF_W1T + 64 * 128 * 2)              // 3x64 fp32
#define OFF_B1F  (OFF_W1POS + 768)
#define OFF_W2T  (OFF_B1F + 256)                        // 64x64 bf16
#define OFF_B2F  (OFF_W2T + 64 * 64 * 2)

// ---------------- prep: fold BN into conv weights, transpose to [tap][co][ci] bf16 ----------------
__global__ void prep_weights(const float* __restrict__ cw1, const float* __restrict__ cb1,
                             const float* __restrict__ g1, const float* __restrict__ bb1,
                             const float* __restrict__ m1, const float* __restrict__ v1,
                             const float* __restrict__ cw2, const float* __restrict__ cb2,
                             const float* __restrict__ g2, const float* __restrict__ bb2,
                             const float* __restrict__ m2, const float* __restrict__ v2,
                             unsigned short* __restrict__ Wb1, unsigned short* __restrict__ Wb2,
                             float* __restrict__ bias1, float* __restrict__ bias2) {
    int idx = blockIdx.x * 256 + threadIdx.x;           // 0 .. 73727
    int l = idx / 36864;
    int r = idx - l * 36864;
    int ci = r & 63;
    int co = (r >> 6) & 63;
    int tap = r >> 12;
    const float* w  = l ? cw2 : cw1;
    const float* g  = l ? g2  : g1;
    const float* v  = l ? v2  : v1;
    float s = g[co] * rsqrtf(v[co] + 1e-5f);
    float wv = w[(co * 64 + ci) * 9 + tap] * s;
    (l ? Wb2 : Wb1)[(tap * 64 + co) * 64 + ci] = f2bf(wv);
    if (tap == 0 && ci == 0) {
        const float* cb = l ? cb2 : cb1;
        const float* bb = l ? bb2 : bb1;
        const float* m  = l ? m2  : m1;
        (l ? bias2 : bias1)[co] = s * (cb[co] - m[co]) + bb[co];
    }
}

// ---------------- prep: MLP weights -> bf16 transposed (K=128), pos rows fp32, BN1 folded ----------------
__global__ void prep_mlp(const float* __restrict__ w1, const float* __restrict__ b1,
                         const float* __restrict__ g, const float* __restrict__ bb,
                         const float* __restrict__ m, const float* __restrict__ v,
                         const float* __restrict__ w2, const float* __restrict__ b2,
                         unsigned short* __restrict__ w1T, float* __restrict__ w1pos,
                         float* __restrict__ b1f,
                         unsigned short* __restrict__ w2T, float* __restrict__ b2f) {
    int idx = blockIdx.x * 256 + threadIdx.x;   // 0..8191
    if (idx < 8192) {
        int co = idx >> 7, k = idx & 127;
        float rs = g[co] * rsqrtf(v[co] + 1e-5f);
        w1T[idx] = f2bf(w1[k * 64 + co] * rs);
        if (k < 3) w1pos[k * 64 + co] = w1[(128 + k) * 64 + co] * rs;
        if (k == 0) b1f[co] = (b1[co] - m[co]) * rs + bb[co];
    }
    if (idx < 4096) {
        int co = idx >> 6, k = idx & 63;
        w2T[idx] = f2bf(w2[k * 64 + co]);
        if (k == 0) b2f[co] = b2[co];
    }
}

// ---------------- zero the 1-pixel pad ring of buf2 ----------------
__global__ void ring_zero(unsigned short* __restrict__ buf2) {
    int idx = blockIdx.x * 256 + threadIdx.x;       // one uint4 (8 ch) each
    if (idx >= 4 * 1028 * 8) return;
    int c8 = idx & 7;
    int rest = idx >> 3;
    int p = rest % 1028;
    int b = rest / 1028;
    int x, y;
    if (p < 258)      { y = 0;   x = p; }
    else if (p < 516) { y = 257; x = p - 258; }
    else if (p < 772) { x = 0;   y = p - 516 + 1; }
    else              { x = 257; y = p - 772 + 1; }
    unsigned short* dst = buf2 + (((b * HP + y) * WP + x) * 64 + c8 * 8);
    uint4 z = {0u, 0u, 0u, 0u};
    *reinterpret_cast<uint4*>(dst) = z;
}

// ---------------- point MLP (bf16 MFMA, A direct from global) + coalesced scatter-max ----------------
// 128 points/block, 4 fully independent waves (no barriers); wave w owns points [w*32, w*32+32).
#define HSTR 72
#define VSTR 68
__global__ __launch_bounds__(256) void mlp_gemm_scatter(
        const float* __restrict__ points, const float* __restrict__ features,
        const unsigned short* __restrict__ w1T, const float* __restrict__ w1pos,
        const float* __restrict__ b1f,
        const unsigned short* __restrict__ w2T, const float* __restrict__ b2f,
        float* __restrict__ bev /* (B,H,W,64) fp32 (bf16-valued), zero-init */) {
    __shared__ unsigned short ldsH[128 * HSTR];     // h, bf16, A-layout (wave-private rows)
    __shared__ unsigned short ldsV[128 * VSTR];     // out transpose, bf16 (wave-private rows)
    __shared__ float4 ldsPos[128];                  // posx,posy,posz, cell(int bits)

    const int tid = threadIdx.x;
    const int w = tid >> 6, lane = tid & 63, n = lane & 15, q = lane >> 4;
    const int m0 = w * 32;
    const long pt0 = (long)blockIdx.x * 128;

    // ---- pos/cell for this wave's 32 points (lanes 0..31) ----
    if (lane < 32) {
        const long pt = pt0 + m0 + lane;
        const float x = points[pt * 3 + 0];
        const float y = points[pt * 3 + 1];
        const float z = points[pt * 3 + 2];
        const bool valid = (x >= -50.f) & (x < 50.f) & (y >= -50.f) & (y < 50.f) &
                           (z >= -3.f) & (z < 5.f);
        int cell = -1;
        if (valid) {
            int col = (int)((x + 50.f) / 0.390625f); col = min(max(col, 0), 255);
            int row = (int)((y + 50.f) / 0.390625f); row = min(max(row, 0), 255);
            int b = pt >= 300000 ? 3 : (pt >= 200000 ? 2 : (pt >= 100000 ? 1 : 0));
            cell = (b * HH + row) * WW + col;
        }
        float4 v;
        v.x = (x + 50.f) * 0.01f;
        v.y = (y + 50.f) * 0.01f;
        v.z = (z + 3.f) * 0.125f;
        v.w = __int_as_float(cell);
        ldsPos[m0 + lane] = v;
    }

    // ---- GEMM1: (32 x 128) x (128 x 64) per wave, A direct from global fp32 ----
    floatx4 acc[2][4];
    #pragma unroll
    for (int mt = 0; mt < 2; ++mt)
        #pragma unroll
        for (int nt = 0; nt < 4; ++nt) acc[mt][nt] = (floatx4){0.f, 0.f, 0.f, 0.f};

    #pragma unroll
    for (int ks = 0; ks < 4; ++ks) {
        short8 bf[4];
        #pragma unroll
        for (int nt = 0; nt < 4; ++nt)
            bf[nt] = *reinterpret_cast<const short8*>(w1T + (nt * 16 + n) * 128 + ks * 32 + q * 8);
        #pragma unroll
        for (int mt = 0; mt < 2; ++mt) {
            short8 a = cvt8(features + (pt0 + m0 + mt * 16 + n) * CIN + ks * 32 + q * 8);
            #pragma unroll
            for (int nt = 0; nt < 4; ++nt)
                acc[mt][nt] = __builtin_amdgcn_mfma_f32_16x16x32_bf16(a, bf[nt], acc[mt][nt], 0, 0, 0);
        }
    }

    // pos rank-3 update weights + bias (fp32, exact)
    float w1p[3][4], bs1[4];
    #pragma unroll
    for (int nt = 0; nt < 4; ++nt) {
        bs1[nt] = b1f[nt * 16 + n];
        #pragma unroll
        for (int j = 0; j < 3; ++j) w1p[j][nt] = w1pos[j * 64 + nt * 16 + n];
    }

    // ---- h = relu(acc + bias + pos·w1pos) -> LDS (bf16, A-layout; wave-private rows) ----
    #pragma unroll
    for (int mt = 0; mt < 2; ++mt)
        #pragma unroll
        for (int r = 0; r < 4; ++r) {
            const int mm = m0 + mt * 16 + q * 4 + r;
            const float4 pos = ldsPos[mm];
            #pragma unroll
            for (int nt = 0; nt < 4; ++nt) {
                float hv = acc[mt][nt][r] + bs1[nt]
                         + pos.x * w1p[0][nt] + pos.y * w1p[1][nt] + pos.z * w1p[2][nt];
                ldsH[mm * HSTR + nt * 16 + n] = f2bf(fmaxf(hv, 0.f));
            }
        }

    // ---- GEMM2: (32 x 64) x (64 x 64) per wave ----
    floatx4 acc2[2][4];
    #pragma unroll
    for (int mt = 0; mt < 2; ++mt)
        #pragma unroll
        for (int nt = 0; nt < 4; ++nt) acc2[mt][nt] = (floatx4){0.f, 0.f, 0.f, 0.f};

    #pragma unroll
    for (int ks = 0; ks < 2; ++ks) {
        short8 bf[4];
        #pragma unroll
        for (int nt = 0; nt < 4; ++nt)
            bf[nt] = *reinterpret_cast<const short8*>(w2T + (nt * 16 + n) * 64 + ks * 32 + q * 8);
        #pragma unroll
        for (int mt = 0; mt < 2; ++mt) {
            short8 a = *reinterpret_cast<const short8*>(
                &ldsH[(m0 + mt * 16 + n) * HSTR + ks * 32 + q * 8]);
            #pragma unroll
            for (int nt = 0; nt < 4; ++nt)
                acc2[mt][nt] = __builtin_amdgcn_mfma_f32_16x16x32_bf16(a, bf[nt], acc2[mt][nt], 0, 0, 0);
        }
    }

    float bs2[4];
    #pragma unroll
    for (int nt = 0; nt < 4; ++nt) bs2[nt] = b2f[nt * 16 + n];

    // ---- transpose: clamp, round to bf16 (monotone => output-equivalent), wave-private rows ----
    #pragma unroll
    for (int mt = 0; mt < 2; ++mt)
        #pragma unroll
        for (int r = 0; r < 4; ++r) {
            const int mm = m0 + mt * 16 + q * 4 + r;
            #pragma unroll
            for (int nt = 0; nt < 4; ++nt) {
                float val = fmaxf(acc2[mt][nt][r] + bs2[nt], 0.f);
                ldsV[mm * VSTR + nt * 16 + n] = f2bf(val);
            }
        }

    // ---- scatter: one atomic instruction per valid point, 64 consecutive dwords ----
    #pragma unroll 4
    for (int i = 0; i < 32; ++i) {
        const int p = m0 + i;
        const int cell = __builtin_amdgcn_readfirstlane(__float_as_int(ldsPos[p].w));
        if (cell >= 0) {
            unsigned int bits = (unsigned int)ldsV[p * VSTR + lane] << 16;
            atomicMax((int*)bev + (long)cell * 64 + lane, (int)bits);
        }
    }
}

// ---------------- conv 3x3 64->64, bf16 MFMA implicit GEMM ----------------
// SRCF32: stage from fp32 NHWC bev (B,256,256,64) with boundary predication.
// else: stage from padded bf16 (B,258,258,64).
#define PSTR 72
template <bool FINAL, bool SRCF32>
__global__ __launch_bounds__(256) void conv3x3(const void* __restrict__ Xsrc,
                                               const unsigned short* __restrict__ Wb,
                                               const float* __restrict__ bias,
                                               void* __restrict__ out) {
    __shared__ unsigned short lds[3 * 66 * PSTR];

    const int bx = blockIdx.x;      // x tile (0..3)
    const int by = blockIdx.y;      // y (0..255)
    const int bz = blockIdx.z;      // batch
    const int tid = threadIdx.x;
    const int x0 = bx * 64;

    // stage 3 rows x 66 px x 64 ci (bf16), 16B chunks
    for (int ch = tid; ch < 1584; ch += 256) {
        int flat = ch * 8;
        int r = flat / 4224;            // 66*64
        int rem = flat - r * 4224;
        int p = rem >> 6;
        int ci = rem & 63;
        uint4 v;
        if (SRCF32) {
            int gy = by + r - 1;
            int gx = x0 + p - 1;
            if (gy >= 0 && gy < HH && gx >= 0 && gx < WW) {
                v = cvt8u((const float*)Xsrc + (((bz * HH + gy) * WW) + gx) * 64 + ci);
            } else {
                v = (uint4){0u, 0u, 0u, 0u};
            }
        } else {
            v = *reinterpret_cast<const uint4*>(
                (const unsigned short*)Xsrc + (((bz * HP + by + r) * WP) + x0 + p) * 64 + ci);
        }
        *reinterpret_cast<uint4*>(&lds[(r * 66 + p) * PSTR + ci]) = v;
    }

    const int wv = tid >> 6;
    const int lane = tid & 63;
    const int n = lane & 15;
    const int q = lane >> 4;

    // preload B fragments: Wb[tap][co][ci]
    short8 bfrag[9][2];
    #pragma unroll
    for (int t = 0; t < 9; ++t)
        #pragma unroll
        for (int kk = 0; kk < 2; ++kk)
            bfrag[t][kk] = *reinterpret_cast<const short8*>(
                Wb + ((t * 64 + wv * 16 + n) * 64 + kk * 32 + q * 8));

    __syncthreads();

    floatx4 acc[4];
    #pragma unroll
    for (int mt = 0; mt < 4; ++mt) acc[mt] = (floatx4){0.f, 0.f, 0.f, 0.f};

    #pragma unroll
    for (int t = 0; t < 9; ++t) {
        const int dy = t / 3, dx = t % 3;
        const int rowbase = dy * 66 * PSTR;
        #pragma unroll
        for (int kk = 0; kk < 2; ++kk) {
            const int cio = kk * 32 + q * 8;
            #pragma unroll
            for (int mt = 0; mt < 4; ++mt) {
                const int p = mt * 16 + n + dx;
                short8 a = *reinterpret_cast<const short8*>(&lds[rowbase + p * PSTR + cio]);
                acc[mt] = __builtin_amdgcn_mfma_f32_16x16x32_bf16(a, bfrag[t][kk], acc[mt], 0, 0, 0);
            }
        }
    }

    // epilogue: D layout col=lane&15 (co), row=q*4+reg (pixel)
    const int co = wv * 16 + n;
    const float bs = bias[co];
    #pragma unroll
    for (int mt = 0; mt < 4; ++mt) {
        #pragma unroll
        for (int r = 0; r < 4; ++r) {
            int px = mt * 16 + q * 4 + r;
            float val = fmaxf(acc[mt][r] + bs, 0.f);
            if (FINAL) {
                ((float*)out)[((bz * 64 + co) * HH + by) * WW + x0 + px] = val;
            } else {
                ((unsigned short*)out)[((bz * HP + by + 1) * WP + (x0 + px + 1)) * 64 + co] = f2bf(val);
            }
        }
    }
}

// ---------------- launch ----------------
extern "C" void kernel_launch(void* const* d_in, const int* in_sizes, int n_in,
                              void* d_out, int out_size, void* d_ws, size_t ws_size,
                              hipStream_t stream) {
    const float* points   = (const float*)d_in[0];
    const float* features = (const float*)d_in[1];
    const float* w1   = (const float*)d_in[2];
    const float* b1   = (const float*)d_in[3];
    const float* bn1g = (const float*)d_in[4];
    const float* bn1b = (const float*)d_in[5];
    const float* bn1m = (const float*)d_in[6];
    const float* bn1v = (const float*)d_in[7];
    const float* w2   = (const float*)d_in[8];
    const float* b2   = (const float*)d_in[9];
    const float* cw1  = (const float*)d_in[10];
    const float* cb1  = (const float*)d_in[11];
    const float* cg1  = (const float*)d_in[12];
    const float* cbb1 = (const float*)d_in[13];
    const float* cm1  = (const float*)d_in[14];
    const float* cv1  = (const float*)d_in[15];
    const float* cw2  = (const float*)d_in[16];
    const float* cb2  = (const float*)d_in[17];
    const float* cg2  = (const float*)d_in[18];
    const float* cbb2 = (const float*)d_in[19];
    const float* cm2  = (const float*)d_in[20];
    const float* cv2  = (const float*)d_in[21];

    float* out = (float*)d_out;
    char* ws = (char*)d_ws;
    unsigned short* buf2 = (unsigned short*)(ws + OFF_BUF2);
    unsigned short* Wb1  = (unsigned short*)(ws + OFF_WB1);
    unsigned short* Wb2  = (unsigned short*)(ws + OFF_WB2);
    float* bias1 = (float*)(ws + OFF_BIAS1);
    float* bias2 = (float*)(ws + OFF_BIAS2);
    unsigned short* w1T = (unsigned short*)(ws + OFF_W1T);
    float* w1pos = (float*)(ws + OFF_W1POS);
    float* b1f = (float*)(ws + OFF_B1F);
    unsigned short* w2T = (unsigned short*)(ws + OFF_W2T);
    float* b2f = (float*)(ws + OFF_B2F);

    // d_out doubles as the fp32 bev scatter buffer (B,H,W,64) — must be zero
    hipMemsetAsync(d_out, 0, (size_t)BATCH * HH * WW * COUT * 4, stream);
    ring_zero<<<(4 * 1028 * 8 + 255) / 256, 256, 0, stream>>>(buf2);

    prep_weights<<<288, 256, 0, stream>>>(cw1, cb1, cg1, cbb1, cm1, cv1,
                                          cw2, cb2, cg2, cbb2, cm2, cv2,
                                          Wb1, Wb2, bias1, bias2);
    prep_mlp<<<32, 256, 0, stream>>>(w1, b1, bn1g, bn1b, bn1m, bn1v, w2, b2,
                                     w1T, w1pos, b1f, w2T, b2f);

    mlp_gemm_scatter<<<(BATCH * NPTS) / 128, 256, 0, stream>>>(
        points, features, w1T, w1pos, b1f, w2T, b2f, out);

    dim3 cgrid(WW / 64, HH, BATCH);
    conv3x3<false, true><<<cgrid, 256, 0, stream>>>((const void*)out, Wb1, bias1, (void*)buf2);
    conv3x3<true, false><<<cgrid, 256, 0, stream>>>((const void*)buf2, Wb2, bias2, (void*)out);
}